// Round 2
// baseline (295.973 us; speedup 1.0000x reference)
//
#include <hip/hip_runtime.h>
#include <math.h>

// Problem shape (fixed by reference)
static constexpr int NB = 16;
static constexpr int NC = 4;
static constexpr int NH = 512;
static constexpr int NW = 1024;
static constexpr int NROWS = NB * NC * NH;   // 32768
static constexpr int NBC   = NB * NC;        // 64

// ---------------------------------------------------------------------------
// Kernel A: one 64-lane wave per (b,c,h) row.
//   - coalesced float4 scan of cls_true row -> first-argmax (val, idx)
//   - lane 0 gathers offset_pred/true at idx, applies vertical mask,
//     writes per-row abs_err and mask to workspace.
// ---------------------------------------------------------------------------
__global__ __launch_bounds__(256) void rowmax_gather_kernel(
    const float* __restrict__ offset_pred,
    const float* __restrict__ offset_true,
    const float* __restrict__ cls_true,
    const float* __restrict__ vertical_true,
    float* __restrict__ err_out,    // [NROWS]
    float* __restrict__ mask_out)   // [NROWS]
{
    const int wave = (blockIdx.x * blockDim.x + threadIdx.x) >> 6;  // row id
    const int lane = threadIdx.x & 63;

    const float* __restrict__ row = cls_true + (size_t)wave * NW;

    float best = -INFINITY;
    int   bidx = 0;
    // lane's 16 elements are at ascending indices -> strict '>' keeps first max
    #pragma unroll
    for (int j = 0; j < 4; ++j) {
        const int base = 4 * (lane + 64 * j);
        const float4 v = *reinterpret_cast<const float4*>(row + base);
        if (v.x > best) { best = v.x; bidx = base + 0; }
        if (v.y > best) { best = v.y; bidx = base + 1; }
        if (v.z > best) { best = v.z; bidx = base + 2; }
        if (v.w > best) { best = v.w; bidx = base + 3; }
    }

    // Wave butterfly reduction on (val, idx): larger val wins; tie -> smaller idx.
    // Per-lane candidates are at ascending W-index per lane, and lanes cover
    // interleaved indices, so lexicographic (max val, min idx) == first-max.
    #pragma unroll
    for (int m = 32; m >= 1; m >>= 1) {
        const float oval = __shfl_xor(best, m, 64);
        const int   oidx = __shfl_xor(bidx, m, 64);
        if (oval > best || (oval == best && oidx < bidx)) { best = oval; bidx = oidx; }
    }

    if (lane == 0) {
        const size_t off = (size_t)wave * NW + (size_t)bidx;
        const float p = offset_pred[off];
        const float t = offset_true[off];
        const float m = (vertical_true[wave] >= 0.5f) ? 1.0f : 0.0f;
        err_out[wave]  = fabsf(p - t) * m;
        mask_out[wave] = m;
    }
}

// ---------------------------------------------------------------------------
// Kernel B (fused finisher): single block, 1024 threads (16 waves).
//   Each wave reduces 4 consecutive (b,c) groups (512 rows each) to
//   per_bc = cnt>0 ? sum/max(cnt,1) : 0 in LDS; then wave 0 sums the 64
//   per-bc values and writes sum/NB. Fully deterministic.
// ---------------------------------------------------------------------------
__global__ __launch_bounds__(1024) void finish_kernel(
    const float* __restrict__ err,
    const float* __restrict__ mask,
    float* __restrict__ out)
{
    const int t    = threadIdx.x;
    const int wave = t >> 6;        // 0..15
    const int lane = t & 63;

    __shared__ float lbc[NBC];

    #pragma unroll
    for (int g = 0; g < 4; ++g) {
        const int bc = wave * 4 + g;                // 0..63
        const float* __restrict__ e = err  + (size_t)bc * NH;
        const float* __restrict__ k = mask + (size_t)bc * NH;

        // 512 values per group, 64 lanes -> 8 each (coalesced).
        float se = 0.0f, sm = 0.0f;
        #pragma unroll
        for (int j = 0; j < 8; ++j) {
            se += e[lane + 64 * j];
            sm += k[lane + 64 * j];
        }
        #pragma unroll
        for (int m = 32; m >= 1; m >>= 1) {
            se += __shfl_xor(se, m, 64);
            sm += __shfl_xor(sm, m, 64);
        }
        if (lane == 0)
            lbc[bc] = (sm > 0.0f) ? (se / fmaxf(sm, 1.0f)) : 0.0f;
    }

    __syncthreads();

    if (wave == 0) {
        float v = lbc[lane];
        #pragma unroll
        for (int m = 32; m >= 1; m >>= 1) v += __shfl_xor(v, m, 64);
        if (lane == 0) out[0] = v / (float)NB;
    }
}

// ---------------------------------------------------------------------------
extern "C" void kernel_launch(void* const* d_in, const int* in_sizes, int n_in,
                              void* d_out, int out_size, void* d_ws, size_t ws_size,
                              hipStream_t stream) {
    const float* offset_pred   = (const float*)d_in[0];
    const float* offset_true   = (const float*)d_in[1];
    const float* cls_true      = (const float*)d_in[2];
    const float* vertical_true = (const float*)d_in[3];
    float* out = (float*)d_out;

    float* ws_err  = (float*)d_ws;               // NROWS floats
    float* ws_mask = ws_err + NROWS;             // NROWS floats

    // Kernel A: 32768 waves -> 8192 blocks of 256 threads (4 waves each).
    rowmax_gather_kernel<<<NROWS / 4, 256, 0, stream>>>(
        offset_pred, offset_true, cls_true, vertical_true, ws_err, ws_mask);

    // Fused finisher: one block.
    finish_kernel<<<1, 1024, 0, stream>>>(ws_err, ws_mask, out);
}

// Round 4
// 287.749 us; speedup vs baseline: 1.0286x; 1.0286x over previous
//
#include <hip/hip_runtime.h>
#include <math.h>

// Problem shape (fixed by reference)
static constexpr int NB = 16;
static constexpr int NC = 4;
static constexpr int NH = 512;
static constexpr int NW = 1024;
static constexpr int NROWS = NB * NC * NH;   // 32768
static constexpr int NBC   = NB * NC;        // 64

// Native clang vector type — accepted by __builtin_nontemporal_load
// (HIP_vector_type float4 is a struct and is rejected).
typedef float f32x4 __attribute__((ext_vector_type(4)));

// ---------------------------------------------------------------------------
// Kernel A: one 64-lane wave per (b,c,h) row.
//   - coalesced, NON-TEMPORAL float4 scan of cls_true row -> first-argmax
//   - lane 0 gathers offset_pred/true at idx, applies vertical mask,
//     writes packed (abs_err, mask) float2 to workspace.
// ---------------------------------------------------------------------------
__global__ __launch_bounds__(256) void rowmax_gather_kernel(
    const float* __restrict__ offset_pred,
    const float* __restrict__ offset_true,
    const float* __restrict__ cls_true,
    const float* __restrict__ vertical_true,
    float2* __restrict__ em_out)    // [NROWS] (.x = abs_err, .y = mask)
{
    const int wave = (blockIdx.x * blockDim.x + threadIdx.x) >> 6;  // row id
    const int lane = threadIdx.x & 63;

    const float* __restrict__ row = cls_true + (size_t)wave * NW;

    // Streaming read: cls_true is consumed exactly once -> non-temporal.
    const f32x4 v0 = __builtin_nontemporal_load(reinterpret_cast<const f32x4*>(row + 4 * lane));
    const f32x4 v1 = __builtin_nontemporal_load(reinterpret_cast<const f32x4*>(row + 4 * (lane + 64)));
    const f32x4 v2 = __builtin_nontemporal_load(reinterpret_cast<const f32x4*>(row + 4 * (lane + 128)));
    const f32x4 v3 = __builtin_nontemporal_load(reinterpret_cast<const f32x4*>(row + 4 * (lane + 192)));

    float best = -INFINITY;
    int   bidx = 0;
    // Ascending index order per lane + strict '>' keeps the FIRST max.
    {
        const int b0 = 4 * lane;
        if (v0[0] > best) { best = v0[0]; bidx = b0 + 0; }
        if (v0[1] > best) { best = v0[1]; bidx = b0 + 1; }
        if (v0[2] > best) { best = v0[2]; bidx = b0 + 2; }
        if (v0[3] > best) { best = v0[3]; bidx = b0 + 3; }
        const int b1 = 4 * (lane + 64);
        if (v1[0] > best) { best = v1[0]; bidx = b1 + 0; }
        if (v1[1] > best) { best = v1[1]; bidx = b1 + 1; }
        if (v1[2] > best) { best = v1[2]; bidx = b1 + 2; }
        if (v1[3] > best) { best = v1[3]; bidx = b1 + 3; }
        const int b2 = 4 * (lane + 128);
        if (v2[0] > best) { best = v2[0]; bidx = b2 + 0; }
        if (v2[1] > best) { best = v2[1]; bidx = b2 + 1; }
        if (v2[2] > best) { best = v2[2]; bidx = b2 + 2; }
        if (v2[3] > best) { best = v2[3]; bidx = b2 + 3; }
        const int b3 = 4 * (lane + 192);
        if (v3[0] > best) { best = v3[0]; bidx = b3 + 0; }
        if (v3[1] > best) { best = v3[1]; bidx = b3 + 1; }
        if (v3[2] > best) { best = v3[2]; bidx = b3 + 2; }
        if (v3[3] > best) { best = v3[3]; bidx = b3 + 3; }
    }

    // Wave butterfly on (val, idx): larger val wins; tie -> smaller idx.
    // Lexicographic (max val, min idx) == first-max across the whole row.
    #pragma unroll
    for (int m = 32; m >= 1; m >>= 1) {
        const float oval = __shfl_xor(best, m, 64);
        const int   oidx = __shfl_xor(bidx, m, 64);
        if (oval > best || (oval == best && oidx < bidx)) { best = oval; bidx = oidx; }
    }

    if (lane == 0) {
        const size_t off = (size_t)wave * NW + (size_t)bidx;
        const float p = offset_pred[off];
        const float t = offset_true[off];
        const float m = (vertical_true[wave] >= 0.5f) ? 1.0f : 0.0f;
        em_out[wave] = make_float2(fabsf(p - t) * m, m);
    }
}

// ---------------------------------------------------------------------------
// Kernel B (fused finisher): single block, 1024 threads (16 waves).
//   Each wave reduces 4 consecutive (b,c) groups (512 rows each) to
//   per_bc = cnt>0 ? sum/max(cnt,1) : 0 in LDS; then wave 0 sums the 64
//   per-bc values and writes sum/NB. Fully deterministic.
// ---------------------------------------------------------------------------
__global__ __launch_bounds__(1024) void finish_kernel(
    const float2* __restrict__ em,
    float* __restrict__ out)
{
    const int t    = threadIdx.x;
    const int wave = t >> 6;        // 0..15
    const int lane = t & 63;

    __shared__ float lbc[NBC];

    #pragma unroll
    for (int g = 0; g < 4; ++g) {
        const int bc = wave * 4 + g;                // 0..63
        const float2* __restrict__ e = em + (size_t)bc * NH;

        // 512 float2 per group, 64 lanes -> 8 each (coalesced 8B/lane).
        float se = 0.0f, sm = 0.0f;
        #pragma unroll
        for (int j = 0; j < 8; ++j) {
            const float2 v = e[lane + 64 * j];
            se += v.x;
            sm += v.y;
        }
        #pragma unroll
        for (int m = 32; m >= 1; m >>= 1) {
            se += __shfl_xor(se, m, 64);
            sm += __shfl_xor(sm, m, 64);
        }
        if (lane == 0)
            lbc[bc] = (sm > 0.0f) ? (se / fmaxf(sm, 1.0f)) : 0.0f;
    }

    __syncthreads();

    if (wave == 0) {
        float v = lbc[lane];
        #pragma unroll
        for (int m = 32; m >= 1; m >>= 1) v += __shfl_xor(v, m, 64);
        if (lane == 0) out[0] = v / (float)NB;
    }
}

// ---------------------------------------------------------------------------
extern "C" void kernel_launch(void* const* d_in, const int* in_sizes, int n_in,
                              void* d_out, int out_size, void* d_ws, size_t ws_size,
                              hipStream_t stream) {
    const float* offset_pred   = (const float*)d_in[0];
    const float* offset_true   = (const float*)d_in[1];
    const float* cls_true      = (const float*)d_in[2];
    const float* vertical_true = (const float*)d_in[3];
    float* out = (float*)d_out;

    float2* ws_em = (float2*)d_ws;               // NROWS float2 = 256 KiB

    // Kernel A: 32768 waves -> 8192 blocks of 256 threads (4 waves each).
    rowmax_gather_kernel<<<NROWS / 4, 256, 0, stream>>>(
        offset_pred, offset_true, cls_true, vertical_true, ws_em);

    // Fused finisher: one block.
    finish_kernel<<<1, 1024, 0, stream>>>(ws_em, out);
}